// Round 1
// 116.307 us; speedup vs baseline: 1.1343x; 1.1343x over previous
//
#include <hip/hip_runtime.h>
#include <math.h>

#define CH_STRIDE (512 * 512)

// f32 DCT matrix = float32(float64 0.5*cos((2x+1)u*pi/16), row0 /sqrt2) — matches asarray(D, float32)
static constexpr float DMc[8][8] = {
  { 0.35355339059327373f, 0.35355339059327373f, 0.35355339059327373f, 0.35355339059327373f,
    0.35355339059327373f, 0.35355339059327373f, 0.35355339059327373f, 0.35355339059327373f},
  { 0.49039264020161522f, 0.41573480615127262f, 0.27778511650980111f, 0.09754516100806413f,
   -0.09754516100806413f,-0.27778511650980111f,-0.41573480615127262f,-0.49039264020161522f},
  { 0.46193976625564337f, 0.19134171618254489f,-0.19134171618254489f,-0.46193976625564337f,
   -0.46193976625564337f,-0.19134171618254489f, 0.19134171618254489f, 0.46193976625564337f},
  { 0.41573480615127262f,-0.09754516100806413f,-0.49039264020161522f,-0.27778511650980111f,
    0.27778511650980111f, 0.49039264020161522f, 0.09754516100806413f,-0.41573480615127262f},
  { 0.35355339059327373f,-0.35355339059327373f,-0.35355339059327373f, 0.35355339059327373f,
    0.35355339059327373f,-0.35355339059327373f,-0.35355339059327373f, 0.35355339059327373f},
  { 0.27778511650980111f,-0.49039264020161522f, 0.09754516100806413f, 0.41573480615127262f,
   -0.41573480615127262f,-0.09754516100806413f, 0.49039264020161522f,-0.27778511650980111f},
  { 0.19134171618254489f,-0.46193976625564337f, 0.46193976625564337f,-0.19134171618254489f,
   -0.19134171618254489f, 0.46193976625564337f,-0.46193976625564337f, 0.19134171618254489f},
  { 0.09754516100806413f,-0.27778511650980111f, 0.41573480615127262f,-0.49039264020161522f,
    0.49039264020161522f,-0.41573480615127262f, 0.27778511650980111f,-0.09754516100806413f},
};

// q = float32(table) * 0.5f — exact halves. [0..63]=Y[u][v], [64..127]=C.
static constexpr float QTABc[128] = {
   8.0f,  5.5f,  5.0f,  8.0f, 12.0f, 20.0f, 25.5f, 30.5f,
   6.0f,  6.0f,  7.0f,  9.5f, 13.0f, 29.0f, 30.0f, 27.5f,
   7.0f,  6.5f,  8.0f, 12.0f, 20.0f, 28.5f, 34.5f, 28.0f,
   7.0f,  8.5f, 11.0f, 14.5f, 25.5f, 43.5f, 40.0f, 31.0f,
   9.0f, 11.0f, 18.5f, 28.0f, 34.0f, 54.5f, 51.5f, 38.5f,
  12.0f, 17.5f, 27.5f, 32.0f, 40.5f, 52.0f, 56.5f, 46.0f,
  24.5f, 32.0f, 39.0f, 43.5f, 51.5f, 60.5f, 60.0f, 50.5f,
  36.0f, 46.0f, 47.5f, 49.0f, 56.0f, 50.0f, 51.5f, 49.5f,

   8.5f,  9.0f, 12.0f, 23.5f, 49.5f, 49.5f, 49.5f, 49.5f,
   9.0f, 10.5f, 13.0f, 33.0f, 49.5f, 49.5f, 49.5f, 49.5f,
  12.0f, 13.0f, 28.0f, 49.5f, 49.5f, 49.5f, 49.5f, 49.5f,
  23.5f, 33.0f, 49.5f, 49.5f, 49.5f, 49.5f, 49.5f, 49.5f,
  49.5f, 49.5f, 49.5f, 49.5f, 49.5f, 49.5f, 49.5f, 49.5f,
  49.5f, 49.5f, 49.5f, 49.5f, 49.5f, 49.5f, 49.5f, 49.5f,
  49.5f, 49.5f, 49.5f, 49.5f, 49.5f, 49.5f, 49.5f, 49.5f,
  49.5f, 49.5f, 49.5f, 49.5f, 49.5f, 49.5f, 49.5f, 49.5f,
};

// correctly-rounded f32 ops, no contraction — each maps to one numpy C op
__device__ __forceinline__ float fm(float a, float b) { return __fmul_rn(a, b); }
__device__ __forceinline__ float fa(float a, float b) { return __fadd_rn(a, b); }
__device__ __forceinline__ float fs(float a, float b) { return __fsub_rn(a, b); }
__device__ __forceinline__ float fd(float a, float b) { return __fdiv_rn(a, b); }

// One workgroup = one 32x32 pixel tile of one image.
//   stage1: all 256 threads load/convert; chroma 2x2 mean in-register via shfl_xor(8)
//   einsums: 24 DCT blocks (16 Y + 4 Cb + 4 Cr) x 8 rows = 192 tasks = waves 0..2 FULL,
//            wave 3 branches past (an idle wave costs no VALU issue; idle lanes would).
//   Register-lean restructure of both einsums keeps every accumulator's term ORDER
//   bit-identical to the previous (verified) kernel; only thread assignment changed.
__global__ __launch_bounds__(256, 4)
void jpeg_kernel(const float* __restrict__ x, float* __restrict__ out) {
  const int tid = threadIdx.x;
  const int q  = blockIdx.x;           // 0..4095
  const int b  = q >> 8;               // image 0..15
  const int qq = q & 255;
  const int row0 = (qq >> 4) << 5;     // 32-px tile row
  const int col0 = (qq & 15) << 5;

  __shared__ __align__(16) float Ys[32][36];     // centered Y, then recon y_r (stride 36: 16B-aligned rows, 2-way banks)
  __shared__ __align__(16) float CbBlk[16][20];  // subsampled, -128 (einsum input)
  __shared__ __align__(16) float CrBlk[16][20];
  __shared__ __align__(16) float Cq[24][8][9];   // quantized coefs [blk][u][v] (stride 9: 2-way banks)
  __shared__ __align__(16) float CbR[16][20];    // chroma recon: fl(fl(rec+128)-128)
  __shared__ __align__(16) float CrR[16][20];

  const int pr = tid >> 3;             // pixel row 0..31
  const int pc = (tid & 7) << 2;       // pixel col 0,4,...,28
  const size_t ibase = ((((size_t)b * 3) * 512 + (size_t)(row0 + pr)) * 512) + (size_t)(col0 + pc);

  // ---------------- Stage 1: load, clip, *255, color convert (strict f32, no FMA) ----------------
  {
    float4 rv = *(const float4*)(x + ibase);
    float4 gv = *(const float4*)(x + ibase + CH_STRIDE);
    float4 bv = *(const float4*)(x + ibase + 2 * CH_STRIDE);
    float xr[4] = {rv.x, rv.y, rv.z, rv.w};
    float xg[4] = {gv.x, gv.y, gv.z, gv.w};
    float xb[4] = {bv.x, bv.y, bv.z, bv.w};
    float yo[4], cbv[4], crv[4];
#pragma unroll
    for (int i = 0; i < 4; ++i) {
      float r  = fm(fminf(fmaxf(xr[i], 0.0f), 1.0f), 255.0f);
      float g  = fm(fminf(fmaxf(xg[i], 0.0f), 1.0f), 255.0f);
      float bb = fm(fminf(fmaxf(xb[i], 0.0f), 1.0f), 255.0f);
      float y  = fa(fa(fm(0.299f, r), fm(0.587f, g)), fm(0.114f, bb));
      yo[i]  = fs(y, 128.0f);
      cbv[i] = fa(fa(fs(fm(-0.168736f, r), fm(0.331264f, g)), fm(0.5f, bb)), 128.0f);
      crv[i] = fa(fs(fs(fm(0.5f, r), fm(0.418688f, g)), fm(0.081312f, bb)), 128.0f);
    }
    *(float4*)&Ys[pr][pc] = make_float4(yo[0], yo[1], yo[2], yo[3]);

    // chroma 2x2 mean — pairwise (c00+c01)+(c10+c11), exact /4 as *0.25f (power-of-2, bit-equal)
    float cbh0 = fa(cbv[0], cbv[1]), cbh1 = fa(cbv[2], cbv[3]);
    float crh0 = fa(crv[0], crv[1]), crh1 = fa(crv[2], crv[3]);
    float pcb0 = __shfl_xor(cbh0, 8, 64);   // partner = adjacent pixel row, same cols
    float pcb1 = __shfl_xor(cbh1, 8, 64);
    float pcr0 = __shfl_xor(crh0, 8, 64);
    float pcr1 = __shfl_xor(crh1, 8, 64);
    if (((tid >> 3) & 1) == 0) {            // even pixel row: owns the 2x2 output
      const int ii = pr >> 1, jc = pc >> 1;
      CbBlk[ii][jc]     = fs(fm(fa(cbh0, pcb0), 0.25f), 128.0f);
      CbBlk[ii][jc + 1] = fs(fm(fa(cbh1, pcb1), 0.25f), 128.0f);
      CrBlk[ii][jc]     = fs(fm(fa(crh0, pcr0), 0.25f), 128.0f);
      CrBlk[ii][jc + 1] = fs(fm(fa(crh1, pcr1), 0.25f), 128.0f);
    }
  }
  __syncthreads();

  // Task mapping: tid<192, blk = tid>>3 (0..15 Y, 16..19 Cb, 20..23 Cr), j = tid&7 (row u / recon row x)
  const int  blk = tid >> 3;
  const int  j   = tid & 7;
  const bool act = tid < 192;
  const bool isY = blk < 16;
  const float* src  = nullptr;   // 8x8 block base in LDS
  float*       wdst = nullptr;   // recon row dest
  int ld = 36;
  const float* qr = QTABc + j * 8;
  if (act) {
    if (isY) {
      const int by = blk >> 2, bx = blk & 3;
      src = &Ys[by * 8][bx * 8];  wdst = &Ys[by * 8 + j][bx * 8];  ld = 36;
    } else if (blk < 20) {
      const int c = blk - 16, cy = c >> 1, cx = c & 1;
      src = &CbBlk[cy * 8][cx * 8];  wdst = &CbR[cy * 8 + j][cx * 8];  ld = 20;  qr += 64;
    } else {
      const int c = blk - 20, cy = c >> 1, cx = c & 1;
      src = &CrBlk[cy * 8][cx * 8];  wdst = &CrR[cy * 8 + j][cx * 8];  ld = 20;  qr += 64;
    }
  }

  // ======= einsum1 'bhwxy,ux,vy->bhwuv' — np c_einsum outstride0_three, SIMD 4-lane =======
  // Register-lean form: per xx row, accumulate m=2xx then m=2xx+1 into s[v][l].
  // Each accumulator s[v][l] receives EXACTLY the original term sequence
  //   m=0..15: fa(s, fm(t0[4m+l], DMc[v][(4m+l)&7]))  with t0[8xx+yy]=fm(blk[xx][yy],DMc[j][xx]),
  // then coef = fa(fa(s0,s1),fa(s2,s3)) (SSE3 hadd tree) — bit-identical, 32+8 regs instead of 64.
  if (act) {
    float dj[8];
#pragma unroll
    for (int xx = 0; xx < 8; ++xx) dj[xx] = DMc[j][xx];
    float s[8][4];
#pragma unroll
    for (int v = 0; v < 8; ++v) { s[v][0] = 0.0f; s[v][1] = 0.0f; s[v][2] = 0.0f; s[v][3] = 0.0f; }
    const float* srow = src;
#pragma unroll
    for (int xx = 0; xx < 8; ++xx) {
      float4 aq = *(const float4*)(srow);
      float4 bq = *(const float4*)(srow + 4);
      srow += ld;
      float t0r[8] = { fm(aq.x, dj[xx]), fm(aq.y, dj[xx]), fm(aq.z, dj[xx]), fm(aq.w, dj[xx]),
                       fm(bq.x, dj[xx]), fm(bq.y, dj[xx]), fm(bq.z, dj[xx]), fm(bq.w, dj[xx]) };
#pragma unroll
      for (int v = 0; v < 8; ++v) {
        s[v][0] = fa(s[v][0], fm(t0r[0], DMc[v][0]));   // m = 2*xx
        s[v][1] = fa(s[v][1], fm(t0r[1], DMc[v][1]));
        s[v][2] = fa(s[v][2], fm(t0r[2], DMc[v][2]));
        s[v][3] = fa(s[v][3], fm(t0r[3], DMc[v][3]));
        s[v][0] = fa(s[v][0], fm(t0r[4], DMc[v][4]));   // m = 2*xx+1
        s[v][1] = fa(s[v][1], fm(t0r[5], DMc[v][5]));
        s[v][2] = fa(s[v][2], fm(t0r[6], DMc[v][6]));
        s[v][3] = fa(s[v][3], fm(t0r[7], DMc[v][7]));
      }
    }
    float* cq = &Cq[blk][j][0];
#pragma unroll
    for (int v = 0; v < 8; ++v) {
      float coef = fa(fa(s[v][0], s[v][1]), fa(s[v][2], s[v][3]));   // hadd tree
      float qv = qr[v];
      cq[v] = fm(rintf(fd(coef, qv)), qv);                           // round half-even, f32 div
    }
  }
  __syncthreads();

  // ======= einsum2 'bhwuv,ux,vy->bhwxy' — per-element scalar chain, u outer / v inner =======
  // Register-lean: per u, t2r[v]=fm(Cq[u][v],DMc[u][j]); each acc[yy] gets (u,v) terms in the
  // original lexicographic order — bit-identical, 8+8 regs instead of 64.
  if (act) {
    float acc[8];
#pragma unroll
    for (int yy = 0; yy < 8; ++yy) acc[yy] = 0.0f;
    const float* cqb = &Cq[blk][0][0];
#pragma unroll
    for (int u = 0; u < 8; ++u) {
      float du = DMc[u][j];
      float t2r[8];
#pragma unroll
      for (int v = 0; v < 8; ++v) t2r[v] = fm(cqb[u * 9 + v], du);
#pragma unroll
      for (int yy = 0; yy < 8; ++yy) {
#pragma unroll
        for (int v = 0; v < 8; ++v)
          acc[yy] = fa(acc[yy], fm(t2r[v], DMc[v][yy]));             // sequential, per-term rounding
      }
    }
    float r0[8];
#pragma unroll
    for (int yy = 0; yy < 8; ++yy) {
      float rec = fa(acc[yy], 128.0f);
      r0[yy] = isY ? rec : fs(rec, 128.0f);                          // y_r  /  cbm = cb_u - 128
    }
    *(float4*)(wdst)     = make_float4(r0[0], r0[1], r0[2], r0[3]);
    *(float4*)(wdst + 4) = make_float4(r0[4], r0[5], r0[6], r0[7]);
  }
  __syncthreads();

  // ---------------- Stage 5: upsample, YCbCr->RGB (strict), clip, /255, wrapper ----------------
  {
    float4 rv = *(const float4*)(x + ibase);          // re-load x (L1/L2-hot) instead of 12 live VGPRs
    float4 gv = *(const float4*)(x + ibase + CH_STRIDE);
    float4 bv = *(const float4*)(x + ibase + 2 * CH_STRIDE);
    float xr[4] = {rv.x, rv.y, rv.z, rv.w};
    float xg[4] = {gv.x, gv.y, gv.z, gv.w};
    float xb[4] = {bv.x, bv.y, bv.z, bv.w};
    float ro[4], go[4], bo[4];
    const int hr = pr >> 1;
#pragma unroll
    for (int i = 0; i < 4; ++i) {
      float y_r = Ys[pr][pc + i];
      float cbm = CbR[hr][(pc + i) >> 1];
      float crm = CrR[hr][(pc + i) >> 1];
      float r2 = fa(y_r, fm(1.402f, crm));
      float g2 = fs(fs(y_r, fm(0.344136f, cbm)), fm(0.714136f, crm));
      float b2 = fa(y_r, fm(1.772f, cbm));
      float jr = fd(fminf(fmaxf(r2, 0.0f), 255.0f), 255.0f);
      float jg = fd(fminf(fmaxf(g2, 0.0f), 255.0f), 255.0f);
      float jb = fd(fminf(fmaxf(b2, 0.0f), 255.0f), 255.0f);
      ro[i] = fa(xr[i], fs(jr, xr[i]));   // x + (jpeg - x), original unclipped x
      go[i] = fa(xg[i], fs(jg, xg[i]));
      bo[i] = fa(xb[i], fs(jb, xb[i]));
    }
    *(float4*)(out + ibase)                 = make_float4(ro[0], ro[1], ro[2], ro[3]);
    *(float4*)(out + ibase + CH_STRIDE)     = make_float4(go[0], go[1], go[2], go[3]);
    *(float4*)(out + ibase + 2 * CH_STRIDE) = make_float4(bo[0], bo[1], bo[2], bo[3]);
  }
}

extern "C" void kernel_launch(void* const* d_in, const int* in_sizes, int n_in,
                              void* d_out, int out_size, void* d_ws, size_t ws_size,
                              hipStream_t stream) {
  const float* x = (const float*)d_in[0];
  float* out = (float*)d_out;
  jpeg_kernel<<<dim3(4096), dim3(256), 0, stream>>>(x, out);
}